// Round 6
// baseline (693.527 us; speedup 1.0000x reference)
//
#include <hip/hip_runtime.h>

namespace {

constexpr int kB = 8, kCin = 2, kBins = 1024, kFrames = 512;
constexpr int kC = 8, kE = 1024, kN = kB * kFrames; // 4096

typedef _Float16 f16x8 __attribute__((ext_vector_type(8)));
typedef float f32x4 __attribute__((ext_vector_type(4)));

union HPack4 { _Float16 h[4]; uint2 u; };

// split v = h + (l/4096), h/l normal-range f16 (denormal-proof)
__device__ inline void splitf(float v, _Float16& h, _Float16& l) {
    float a = (fabsf(v) >= 6.103515625e-05f) ? v : 0.f;
    _Float16 hh = (_Float16)a;
    h = hh;
    l = (_Float16)((v - (float)hh) * 4096.0f);
}

// ================= conv (fused conv1->lrelu->conv2+skip) =================
// writes f16 split planes V1,V2 in [c][n][k] layout (n = b*512+f, k = bin)
constexpr int BT = 32, FT = 32, XB = BT + 16, HB = BT + 8;

__global__ __launch_bounds__(256) void conv_fused_v2(
    const float* __restrict__ x,
    const float* __restrict__ w1, const float* __restrict__ b1,
    const float* __restrict__ w2, const float* __restrict__ b2,
    const float* __restrict__ wsk, const float* __restrict__ bsk,
    _Float16* __restrict__ V1, float* __restrict__ partials)
{
    __shared__ float xt[kCin][XB][33];
    __shared__ float h1t[kC][HB][33];
    __shared__ float vbuf[BT][33];
    __shared__ float w1s[kC * kCin * 9];
    __shared__ float w2s[kC * kC][12];
    __shared__ float wsks[kC * kCin];
    __shared__ float b1s[kC], b2s[kC], bsks[kC];
    __shared__ float reds[256];

    const int t = threadIdx.x;
    const int bt = blockIdx.x, ft = blockIdx.y, bb = blockIdx.z;
    const int bs = bt * BT, f0 = ft * FT;
    _Float16* V2 = V1 + (size_t)33554432;

    for (int i = t; i < kC * kCin * 9; i += 256) w1s[i] = w1[i];
    for (int i = t; i < 768; i += 256) {
        int cc = i / 12, k = i % 12;
        w2s[cc][k] = (k < 9) ? w2[cc * 9 + k] : 0.f;
    }
    if (t < kC * kCin) wsks[t] = wsk[t];
    if (t < kC) { b1s[t] = b1[t]; b2s[t] = b2[t]; bsks[t] = bsk[t]; }

    // stage x tile [bs-8, bs+40)
    for (int i = t; i < kCin * XB * FT; i += 256) {
        int fi = i % FT, xb = (i / FT) % XB, ci = i / (FT * XB);
        int gb = bs - 8 + xb;
        float v = 0.f;
        if (gb >= 0 && gb < kBins)
            v = x[((bb * kCin + ci) * kBins + gb) * kFrames + f0 + fi];
        xt[ci][xb][fi] = v;
    }
    __syncthreads();

    const int fi = t & 31;
    const int r = t >> 5; // 0..7

    // h1 stage: thread handles cm=r, hb-octets q=0..4 (hb = q*8+jj)
    for (int q = 0; q < 5; q++) {
        float a8[8];
        #pragma unroll
        for (int jj = 0; jj < 8; jj++) a8[jj] = b1s[r];
        #pragma unroll
        for (int ci = 0; ci < kCin; ci++) {
            float w[16];
            #pragma unroll
            for (int k = 0; k < 16; k++) w[k] = xt[ci][q * 8 + k][fi];
            const float* wp = &w1s[(r * kCin + ci) * 9];
            #pragma unroll
            for (int jj = 0; jj < 8; jj++)
                #pragma unroll
                for (int k = 0; k < 9; k++)
                    a8[jj] += w[jj + k] * wp[k];
        }
        #pragma unroll
        for (int jj = 0; jj < 8; jj++) {
            int hb = q * 8 + jj;
            int gb = bs - 4 + hb;
            float v = (gb >= 0 && gb < kBins) ? (a8[jj] > 0.f ? a8[jj] : 0.2f * a8[jj]) : 0.f;
            h1t[r][hb][fi] = v;
        }
    }
    __syncthreads();

    // main stage: thread (fi, r) computes v for 8 c x 4 bins (ob=r*4+j)
    float acc[8][4];
    #pragma unroll
    for (int c = 0; c < 8; c++)
        #pragma unroll
        for (int j = 0; j < 4; j++) acc[c][j] = b2s[c] + bsks[c];

    for (int ci = 0; ci < 8; ci++) {
        float w[12];
        #pragma unroll
        for (int k = 0; k < 12; k++) w[k] = h1t[ci][r * 4 + k][fi];
        #pragma unroll
        for (int c = 0; c < 8; c++) {
            const float4* wp4 = (const float4*)&w2s[c * 8 + ci][0];
            float4 wA = wp4[0], wB = wp4[1], wC = wp4[2];
            float wk[9] = {wA.x, wA.y, wA.z, wA.w, wB.x, wB.y, wB.z, wB.w, wC.x};
            #pragma unroll
            for (int j = 0; j < 4; j++) {
                float s = 0.f;
                #pragma unroll
                for (int k = 0; k < 9; k++) s += w[j + k] * wk[k];
                acc[c][j] += s;
            }
        }
    }
    // skip path
    #pragma unroll
    for (int j = 0; j < 4; j++) {
        float x0 = xt[0][r * 4 + j + 8][fi];
        float x1 = xt[1][r * 4 + j + 8][fi];
        #pragma unroll
        for (int c = 0; c < 8; c++)
            acc[c][j] += x0 * wsks[c * 2] + x1 * wsks[c * 2 + 1];
    }

    float sq = 0.f;
    #pragma unroll
    for (int c = 0; c < 8; c++)
        #pragma unroll
        for (int j = 0; j < 4; j++) sq += acc[c][j] * acc[c][j];

    // retile per channel: vbuf[ob][fi] -> write [n][k] f16 splits
    const int rr = t >> 3, q = t & 7; // rr = n-row 0..31, q = k-quad 0..7
    for (int c = 0; c < 8; c++) {
        __syncthreads();
        #pragma unroll
        for (int j = 0; j < 4; j++) vbuf[r * 4 + j][fi] = acc[c][j];
        __syncthreads();
        HPack4 ph, pl;
        #pragma unroll
        for (int j = 0; j < 4; j++) {
            float v = vbuf[q * 4 + j][rr];
            splitf(v, ph.h[j], pl.h[j]);
        }
        const int n = bb * kFrames + f0 + rr;
        const size_t off = ((size_t)(c * kN + n)) * kBins + bs + q * 4;
        *(uint2*)&V1[off] = ph.u;
        *(uint2*)&V2[off] = pl.u;
    }

    reds[t] = sq;
    __syncthreads();
    for (int off = 128; off > 0; off >>= 1) {
        if (t < off) reds[t] += reds[t + off];
        __syncthreads();
    }
    if (t == 0) {
        int blin = (bb * gridDim.y + blockIdx.y) * gridDim.x + blockIdx.x;
        partials[blin] = reds[0];
    }
}

// ================= codebook split + e2 =================
__global__ __launch_bounds__(256) void cbsplit_e2(
    const float* __restrict__ cb, _Float16* __restrict__ B1,
    float* __restrict__ e2)
{
    const int gw = (blockIdx.x * 256 + threadIdx.x) >> 6;
    const int lane = threadIdx.x & 63;
    _Float16* B2 = B1 + (size_t)8388608;
    const float* row = cb + (size_t)gw * kBins;
    float s = 0.f;
    #pragma unroll
    for (int j = 0; j < 4; j++) {
        float4 v = *(const float4*)&row[lane * 4 + j * 256];
        s += v.x * v.x + v.y * v.y + v.z * v.z + v.w * v.w;
        HPack4 ph, pl;
        splitf(v.x, ph.h[0], pl.h[0]);
        splitf(v.y, ph.h[1], pl.h[1]);
        splitf(v.z, ph.h[2], pl.h[2]);
        splitf(v.w, ph.h[3], pl.h[3]);
        size_t off = (size_t)gw * kBins + lane * 4 + j * 256;
        *(uint2*)&B1[off] = ph.u;
        *(uint2*)&B2[off] = pl.u;
    }
    #pragma unroll
    for (int off = 32; off > 0; off >>= 1) s += __shfl_down(s, off);
    if (lane == 0) e2[gw] = s;
}

// ================= MFMA distance + argmin — barrier-free, reg-resident =====
// flat grid of 512: ch = b&7 (XCD affinity, B panel L2-resident),
// eh = (b>>3)&1 (E half; sibling shares XCD -> A slice L2-shared),
// ntile = b>>4. 128 n-rows x 512 E per block, 4 waves (wm x we = 2x2).
// Fragments loaded straight from global (L1/L2 serve the 2x intra-block
// reuse); no LDS staging, no barriers, no vmcnt drains. Operand values are
// bit-identical to the staged version -> same distances, same argmin.
__global__ __launch_bounds__(256, 2) void dist_mfma(
    const _Float16* __restrict__ V1, const _Float16* __restrict__ B1p,
    const float* __restrict__ e2, unsigned long long* __restrict__ pk)
{
    __shared__ float mv[256];
    __shared__ int miv[256];

    const int t = threadIdx.x;
    const int bidx = blockIdx.x;
    const int ch = bidx & 7;
    const int eh = (bidx >> 3) & 1;
    const int n0 = (bidx >> 4) * 128;
    const int w = t >> 6, lane = t & 63;
    const int l15 = lane & 15, kc4 = lane >> 4;
    const int wm = w >> 1, we = w & 1;

    // per-lane fragment base pointers (k-invariant parts)
    const _Float16* pa1 = V1 + ((size_t)(ch * kN + n0 + wm * 64 + l15)) * kBins + kc4 * 8;
    const _Float16* pa2 = pa1 + (size_t)33554432;           // lo plane
    const _Float16* pb1base = B1p + ((size_t)(ch * kE + eh * 512 + we * 64 + l15)) * kBins + kc4 * 8;
    const float* e2c = e2 + ch * kE;

    float rm[16];
    int ri[16];
    #pragma unroll
    for (int s = 0; s < 16; s++) { rm[s] = 3.4e38f; ri[s] = 0; }

    #pragma unroll 1
    for (int et = 0; et < 4; et++) {
        const _Float16* pb1 = pb1base + (size_t)et * 128 * kBins;
        const _Float16* pb2 = pb1 + (size_t)8388608;        // lo plane

        f32x4 hi[4][4], lo[4][4];
        #pragma unroll
        for (int mi = 0; mi < 4; mi++)
            #pragma unroll
            for (int ei = 0; ei < 4; ei++) {
                hi[mi][ei] = (f32x4){0.f, 0.f, 0.f, 0.f};
                lo[mi][ei] = (f32x4){0.f, 0.f, 0.f, 0.f};
            }

        #pragma unroll 1
        for (int ks = 0; ks < 32; ks++) {
            const int ko = ks * 32;
            f16x8 a1[4], a2[4], b1f[4], b2f[4];
            #pragma unroll
            for (int mi = 0; mi < 4; mi++) {
                a1[mi] = *(const f16x8*)(pa1 + (size_t)mi * 16 * kBins + ko);
                a2[mi] = *(const f16x8*)(pa2 + (size_t)mi * 16 * kBins + ko);
            }
            #pragma unroll
            for (int ei = 0; ei < 4; ei++) {
                b1f[ei] = *(const f16x8*)(pb1 + (size_t)ei * 16 * kBins + ko);
                b2f[ei] = *(const f16x8*)(pb2 + (size_t)ei * 16 * kBins + ko);
            }
            #pragma unroll
            for (int mi = 0; mi < 4; mi++)
                #pragma unroll
                for (int ei = 0; ei < 4; ei++) {
                    hi[mi][ei] = __builtin_amdgcn_mfma_f32_16x16x32_f16(a1[mi], b1f[ei], hi[mi][ei], 0, 0, 0);
                    lo[mi][ei] = __builtin_amdgcn_mfma_f32_16x16x32_f16(a1[mi], b2f[ei], lo[mi][ei], 0, 0, 0);
                    lo[mi][ei] = __builtin_amdgcn_mfma_f32_16x16x32_f16(a2[mi], b1f[ei], lo[mi][ei], 0, 0, 0);
                }
        }

        // epilogue: running argmin (ascending e, strict < keeps first min)
        #pragma unroll
        for (int ei = 0; ei < 4; ei++) {
            const int eix = eh * 512 + et * 128 + we * 64 + ei * 16 + l15;
            const float ev = e2c[eix];
            #pragma unroll
            for (int mi = 0; mi < 4; mi++) {
                f32x4 dot4 = hi[mi][ei] + lo[mi][ei] * (1.0f / 4096.0f);
                #pragma unroll
                for (int rr = 0; rr < 4; rr++) {
                    float d = ev - 2.0f * dot4[rr];
                    int s = mi * 4 + rr;
                    if (d < rm[s]) { rm[s] = d; ri[s] = eix; }
                }
            }
        }
    }

    // cross-lane reduce over the 16 lanes sharing the same rows
    #pragma unroll
    for (int m = 1; m < 16; m <<= 1) {
        #pragma unroll
        for (int s = 0; s < 16; s++) {
            float ov = __shfl_xor(rm[s], m);
            int oi = __shfl_xor(ri[s], m);
            if (ov < rm[s] || (ov == rm[s] && oi < ri[s])) { rm[s] = ov; ri[s] = oi; }
        }
    }

    // merge the 2 waves sharing each row range
    if (l15 == 0) {
        #pragma unroll
        for (int s = 0; s < 16; s++) {
            int mi = s >> 2, rr = s & 3;
            int rloc = wm * 64 + mi * 16 + (lane >> 4) * 4 + rr;
            mv[rloc * 2 + we] = rm[s];
            miv[rloc * 2 + we] = ri[s];
        }
    }
    __syncthreads();
    if (t < 128) {
        float v0 = mv[t * 2], v1 = mv[t * 2 + 1];
        int i0 = miv[t * 2], i1 = miv[t * 2 + 1];
        bool take1 = (v1 < v0) || (v1 == v0 && i1 < i0);
        float bv = take1 ? v1 : v0;
        int bi = take1 ? i1 : i0;
        // packed deterministic cross-block min-merge: sortable f32 | idx
        unsigned int u = __float_as_uint(bv);
        unsigned int su = (u & 0x80000000u) ? ~u : (u ^ 0x80000000u);
        unsigned long long packed = ((unsigned long long)su << 32) | (unsigned int)bi;
        atomicMin(&pk[ch * kN + n0 + t], packed);
    }
}

// ================= gather (reads packed argmin; cp-XCD affine) =============
__global__ __launch_bounds__(256) void gather_pk(
    const float* __restrict__ cb, const unsigned long long* __restrict__ pk,
    float* __restrict__ out)
{
    const int t = threadIdx.x;
    const int lane = t & 63, q = t >> 6;
    const int b = blockIdx.x;
    const int cp = b & 7;            // channel -> XCD affinity (cb panel L2-fits)
    const int bt = (b >> 3) & 63;    // 64 bin-tiles of 16
    const int ftile = (b >> 9) & 7;  // 8 frame tiles of 64
    const int bb = b >> 12;          // batch
    const int co = (kC - 1) - cp;
    const int f = ftile * 64 + lane;
    const int n = bb * kFrames + f;
    const int e = (int)(unsigned int)(pk[cp * kN + n] & 0xFFFFFFFFull);
    const int bin0 = bt * 16 + q * 4;
    const float4 v4 = *(const float4*)&cb[((size_t)cp * kE + e) * kBins + bin0];
    const size_t base = ((size_t)(bb * kC + co) * kBins + bin0) * kFrames + f;
    out[base] = v4.x;
    out[base + kFrames] = v4.y;
    out[base + 2 * (size_t)kFrames] = v4.z;
    out[base + 3 * (size_t)kFrames] = v4.w;
}

// ================= loss (decodes packed min values) =================
__global__ __launch_bounds__(256) void finalize_loss_pk(
    const unsigned long long* __restrict__ pk, const float* __restrict__ partials,
    int npart, float* __restrict__ loss)
{
    __shared__ float reds[256];
    const int t = threadIdx.x;
    float s = 0.f;
    for (int i = t; i < kC * kN; i += 256) {
        unsigned int su = (unsigned int)(pk[i] >> 32);
        unsigned int u = (su & 0x80000000u) ? (su ^ 0x80000000u) : ~su;
        s += __uint_as_float(u);
    }
    for (int i = t; i < npart; i += 256) s += partials[i];
    reds[t] = s;
    __syncthreads();
    for (int off = 128; off > 0; off >>= 1) {
        if (t < off) reds[t] += reds[t + off];
        __syncthreads();
    }
    if (t == 0) loss[0] = 1.25f * reds[0] / (float)(kN * kBins);
}

} // namespace

extern "C" void kernel_launch(void* const* d_in, const int* in_sizes, int n_in,
                              void* d_out, int out_size, void* d_ws, size_t ws_size,
                              hipStream_t stream)
{
    const float* x   = (const float*)d_in[0];
    const float* w1  = (const float*)d_in[1];
    const float* b1  = (const float*)d_in[2];
    const float* w2  = (const float*)d_in[3];
    const float* b2  = (const float*)d_in[4];
    const float* wsk = (const float*)d_in[5];
    const float* bsk = (const float*)d_in[6];
    const float* cb  = (const float*)d_in[7];
    float* out = (float*)d_out;
    char* ws = (char*)d_ws;

    // ws layout: B1|B2 32M | e2 32K | pk 256K | partials 16K
    _Float16* B1 = (_Float16*)ws;
    float* e2                  = (float*)(ws + 33554432);
    unsigned long long* pk     = (unsigned long long*)(ws + 33554432 + 32768);
    float* partials            = (float*)(ws + 33554432 + 32768 + 262144);
    _Float16* V1 = (_Float16*)d_out; // V1 67MB | V2 67MB, overwritten by gather

    hipMemsetAsync(pk, 0xFF, (size_t)kC * kN * 8, stream);
    conv_fused_v2<<<dim3(kBins / BT, kFrames / FT, kB), 256, 0, stream>>>(
        x, w1, b1, w2, b2, wsk, bsk, V1, partials);
    cbsplit_e2<<<(kC * kE) / 4, 256, 0, stream>>>(cb, B1, e2);
    dist_mfma<<<dim3(512), 256, 0, stream>>>(V1, B1, e2, pk);
    gather_pk<<<dim3(32768), 256, 0, stream>>>(cb, pk, out);
    finalize_loss_pk<<<1, 256, 0, stream>>>(pk, partials, 4096,
                                            out + (size_t)kC * kBins * kN);
}

// Round 7
// 418.299 us; speedup vs baseline: 1.6580x; 1.6580x over previous
//
#include <hip/hip_runtime.h>

namespace {

constexpr int kB = 8, kCin = 2, kBins = 1024, kFrames = 512;
constexpr int kC = 8, kE = 1024, kN = kB * kFrames; // 4096

typedef _Float16 f16x8 __attribute__((ext_vector_type(8)));
typedef float f32x4 __attribute__((ext_vector_type(4)));

union HPack4 { _Float16 h[4]; uint2 u; };

// split v = h + (l/4096), h/l normal-range f16 (denormal-proof)
__device__ inline void splitf(float v, _Float16& h, _Float16& l) {
    float a = (fabsf(v) >= 6.103515625e-05f) ? v : 0.f;
    _Float16 hh = (_Float16)a;
    h = hh;
    l = (_Float16)((v - (float)hh) * 4096.0f);
}

// ================= conv (fused conv1->lrelu->conv2+skip) =================
// writes f16 split planes V1,V2 in [c][n][k] layout (n = b*512+f, k = bin)
constexpr int BT = 32, FT = 32, XB = BT + 16, HB = BT + 8;

__global__ __launch_bounds__(256) void conv_fused_v2(
    const float* __restrict__ x,
    const float* __restrict__ w1, const float* __restrict__ b1,
    const float* __restrict__ w2, const float* __restrict__ b2,
    const float* __restrict__ wsk, const float* __restrict__ bsk,
    _Float16* __restrict__ V1, float* __restrict__ partials)
{
    __shared__ float xt[kCin][XB][33];
    __shared__ float h1t[kC][HB][33];
    __shared__ float vbuf[BT][33];
    __shared__ float w1s[kC * kCin * 9];
    __shared__ float w2s[kC * kC][12];
    __shared__ float wsks[kC * kCin];
    __shared__ float b1s[kC], b2s[kC], bsks[kC];
    __shared__ float reds[256];

    const int t = threadIdx.x;
    const int bt = blockIdx.x, ft = blockIdx.y, bb = blockIdx.z;
    const int bs = bt * BT, f0 = ft * FT;
    _Float16* V2 = V1 + (size_t)33554432;

    for (int i = t; i < kC * kCin * 9; i += 256) w1s[i] = w1[i];
    for (int i = t; i < 768; i += 256) {
        int cc = i / 12, k = i % 12;
        w2s[cc][k] = (k < 9) ? w2[cc * 9 + k] : 0.f;
    }
    if (t < kC * kCin) wsks[t] = wsk[t];
    if (t < kC) { b1s[t] = b1[t]; b2s[t] = b2[t]; bsks[t] = bsk[t]; }

    // stage x tile [bs-8, bs+40)
    for (int i = t; i < kCin * XB * FT; i += 256) {
        int fi = i % FT, xb = (i / FT) % XB, ci = i / (FT * XB);
        int gb = bs - 8 + xb;
        float v = 0.f;
        if (gb >= 0 && gb < kBins)
            v = x[((bb * kCin + ci) * kBins + gb) * kFrames + f0 + fi];
        xt[ci][xb][fi] = v;
    }
    __syncthreads();

    const int fi = t & 31;
    const int r = t >> 5; // 0..7

    // h1 stage: thread handles cm=r, hb-octets q=0..4 (hb = q*8+jj)
    for (int q = 0; q < 5; q++) {
        float a8[8];
        #pragma unroll
        for (int jj = 0; jj < 8; jj++) a8[jj] = b1s[r];
        #pragma unroll
        for (int ci = 0; ci < kCin; ci++) {
            float w[16];
            #pragma unroll
            for (int k = 0; k < 16; k++) w[k] = xt[ci][q * 8 + k][fi];
            const float* wp = &w1s[(r * kCin + ci) * 9];
            #pragma unroll
            for (int jj = 0; jj < 8; jj++)
                #pragma unroll
                for (int k = 0; k < 9; k++)
                    a8[jj] += w[jj + k] * wp[k];
        }
        #pragma unroll
        for (int jj = 0; jj < 8; jj++) {
            int hb = q * 8 + jj;
            int gb = bs - 4 + hb;
            float v = (gb >= 0 && gb < kBins) ? (a8[jj] > 0.f ? a8[jj] : 0.2f * a8[jj]) : 0.f;
            h1t[r][hb][fi] = v;
        }
    }
    __syncthreads();

    // main stage: thread (fi, r) computes v for 8 c x 4 bins (ob=r*4+j)
    float acc[8][4];
    #pragma unroll
    for (int c = 0; c < 8; c++)
        #pragma unroll
        for (int j = 0; j < 4; j++) acc[c][j] = b2s[c] + bsks[c];

    for (int ci = 0; ci < 8; ci++) {
        float w[12];
        #pragma unroll
        for (int k = 0; k < 12; k++) w[k] = h1t[ci][r * 4 + k][fi];
        #pragma unroll
        for (int c = 0; c < 8; c++) {
            const float4* wp4 = (const float4*)&w2s[c * 8 + ci][0];
            float4 wA = wp4[0], wB = wp4[1], wC = wp4[2];
            float wk[9] = {wA.x, wA.y, wA.z, wA.w, wB.x, wB.y, wB.z, wB.w, wC.x};
            #pragma unroll
            for (int j = 0; j < 4; j++) {
                float s = 0.f;
                #pragma unroll
                for (int k = 0; k < 9; k++) s += w[j + k] * wk[k];
                acc[c][j] += s;
            }
        }
    }
    // skip path
    #pragma unroll
    for (int j = 0; j < 4; j++) {
        float x0 = xt[0][r * 4 + j + 8][fi];
        float x1 = xt[1][r * 4 + j + 8][fi];
        #pragma unroll
        for (int c = 0; c < 8; c++)
            acc[c][j] += x0 * wsks[c * 2] + x1 * wsks[c * 2 + 1];
    }

    float sq = 0.f;
    #pragma unroll
    for (int c = 0; c < 8; c++)
        #pragma unroll
        for (int j = 0; j < 4; j++) sq += acc[c][j] * acc[c][j];

    // retile per channel: vbuf[ob][fi] -> write [n][k] f16 splits
    const int rr = t >> 3, q = t & 7; // rr = n-row 0..31, q = k-quad 0..7
    for (int c = 0; c < 8; c++) {
        __syncthreads();
        #pragma unroll
        for (int j = 0; j < 4; j++) vbuf[r * 4 + j][fi] = acc[c][j];
        __syncthreads();
        HPack4 ph, pl;
        #pragma unroll
        for (int j = 0; j < 4; j++) {
            float v = vbuf[q * 4 + j][rr];
            splitf(v, ph.h[j], pl.h[j]);
        }
        const int n = bb * kFrames + f0 + rr;
        const size_t off = ((size_t)(c * kN + n)) * kBins + bs + q * 4;
        *(uint2*)&V1[off] = ph.u;
        *(uint2*)&V2[off] = pl.u;
    }

    reds[t] = sq;
    __syncthreads();
    for (int off = 128; off > 0; off >>= 1) {
        if (t < off) reds[t] += reds[t + off];
        __syncthreads();
    }
    if (t == 0) {
        int blin = (bb * gridDim.y + blockIdx.y) * gridDim.x + blockIdx.x;
        partials[blin] = reds[0];
    }
}

// ================= codebook split + e2 (+ pk init, replaces memset) =======
__global__ __launch_bounds__(256) void cbsplit_e2(
    const float* __restrict__ cb, _Float16* __restrict__ B1,
    float* __restrict__ e2, unsigned long long* __restrict__ pk)
{
    // fold the pk initialization into this kernel (saves a dispatch)
    const int gid = blockIdx.x * 256 + threadIdx.x;
    if (gid < kC * kN) pk[gid] = ~0ull;

    const int gw = gid >> 6;
    const int lane = threadIdx.x & 63;
    _Float16* B2 = B1 + (size_t)8388608;
    const float* row = cb + (size_t)gw * kBins;
    float s = 0.f;
    #pragma unroll
    for (int j = 0; j < 4; j++) {
        float4 v = *(const float4*)&row[lane * 4 + j * 256];
        s += v.x * v.x + v.y * v.y + v.z * v.z + v.w * v.w;
        HPack4 ph, pl;
        splitf(v.x, ph.h[0], pl.h[0]);
        splitf(v.y, ph.h[1], pl.h[1]);
        splitf(v.z, ph.h[2], pl.h[2]);
        splitf(v.w, ph.h[3], pl.h[3]);
        size_t off = (size_t)gw * kBins + lane * 4 + j * 256;
        *(uint2*)&B1[off] = ph.u;
        *(uint2*)&B2[off] = pl.u;
    }
    #pragma unroll
    for (int off = 32; off > 0; off >>= 1) s += __shfl_down(s, off);
    if (lane == 0) e2[gw] = s;
}

// ================= MFMA distance + argmin, 2-buffer + 2 blocks/CU ==========
// (round-5 proven kernel, verbatim: 197 us, MfmaUtil ~51%, LDS-issue-bound)
__global__ __launch_bounds__(256, 2) void dist_mfma(
    const _Float16* __restrict__ V1, const _Float16* __restrict__ B1p,
    const float* __restrict__ e2, unsigned long long* __restrict__ pk)
{
    __shared__ char smem[2 * 32768 + 2048];

    const int t = threadIdx.x;
    const int bidx = blockIdx.x;
    const int ch = bidx & 7;
    const int eh = (bidx >> 3) & 1;
    const int n0 = (bidx >> 4) * 128;
    const int w = t >> 6, lane = t & 63;
    const int l15 = lane & 15, kc4 = lane >> 4;
    const int wm = w >> 1, we = w & 1;

    float* lds_e2 = (float*)(smem + 65536);
    {
        const float* e2c = e2 + ch * kE + eh * 512;
        float a = e2c[t], b = e2c[t + 256];
        lds_e2[t] = a;
        lds_e2[t + 256] = b;
    }

    // staging source pointers (K-invariant parts)
    const _Float16* srcA[4];
    const _Float16* srcB[4];
    int dstoff[4];
    #pragma unroll
    for (int i = 0; i < 4; i++) {
        int ci = w * 256 + i * 64 + lane;
        int row = ci >> 3, slot = ci & 7;
        int g = slot ^ (row & 7);
        int p = g >> 2, kc = g & 3;
        srcA[i] = V1 + (size_t)p * 33554432 + ((size_t)(ch * kN + n0 + row)) * kBins + kc * 8;
        srcB[i] = B1p + (size_t)p * 8388608 + ((size_t)(ch * kE + row)) * kBins + kc * 8;
        dstoff[i] = (w * 256 + i * 64) * 16;
    }

    // fragment read bases (XOR-swizzled slots; conflict-free)
    const int rowA = wm * 64 + l15;
    const int rowB = we * 64 + l15;
    const int baseA1 = rowA * 128 + ((kc4) ^ (rowA & 7)) * 16;
    const int baseA2 = rowA * 128 + ((4 + kc4) ^ (rowA & 7)) * 16;
    const int baseB1 = 16384 + rowB * 128 + ((kc4) ^ (rowB & 7)) * 16;
    const int baseB2 = 16384 + rowB * 128 + ((4 + kc4) ^ (rowB & 7)) * 16;

    float rm[16];
    int ri[16];
    #pragma unroll
    for (int s = 0; s < 16; s++) { rm[s] = 3.4e38f; ri[s] = 0; }

    typedef const __attribute__((address_space(1))) void gsrc_t;
    typedef __attribute__((address_space(3))) void gdst_t;

    auto issue = [&](int jj) {
        const int k0 = (jj & 31) * 32;
        const size_t etoff = (size_t)(eh * 4 + (jj >> 5)) * 128 * kBins + k0;
        char* nb = smem + (jj & 1) * 32768;
        #pragma unroll
        for (int i = 0; i < 4; i++)
            __builtin_amdgcn_global_load_lds((gsrc_t*)(srcA[i] + k0), (gdst_t*)(nb + dstoff[i]), 16, 0, 0);
        #pragma unroll
        for (int i = 0; i < 4; i++)
            __builtin_amdgcn_global_load_lds((gsrc_t*)(srcB[i] + etoff), (gdst_t*)(nb + 16384 + dstoff[i]), 16, 0, 0);
    };

    f32x4 hi[4][4], lo[4][4];
    #pragma unroll
    for (int mi = 0; mi < 4; mi++)
        #pragma unroll
        for (int ei = 0; ei < 4; ei++) {
            hi[mi][ei] = (f32x4){0.f, 0.f, 0.f, 0.f};
            lo[mi][ei] = (f32x4){0.f, 0.f, 0.f, 0.f};
        }

    __syncthreads();            // e2 staged (its loads drained); LDS clean

    issue(0);

    #pragma unroll 1
    for (int et = 0; et < 4; et++) {
        #pragma unroll 1
        for (int ks = 0; ks < 32; ks++) {
            const int j = et * 32 + ks;
            // batch j landed; all waves done reading the other buffer ->
            // safe to overwrite it with batch j+1 after the barrier.
            asm volatile("s_waitcnt vmcnt(0)\n\ts_barrier" ::: "memory");
            if (j < 127) issue(j + 1);

            const char* buf = smem + (j & 1) * 32768;
            f16x8 a1[4], a2[4], b1f[4], b2f[4];
            #pragma unroll
            for (int mi = 0; mi < 4; mi++) {
                a1[mi] = *(const f16x8*)(buf + baseA1 + mi * 2048);
                a2[mi] = *(const f16x8*)(buf + baseA2 + mi * 2048);
            }
            #pragma unroll
            for (int ei = 0; ei < 4; ei++) {
                b1f[ei] = *(const f16x8*)(buf + baseB1 + ei * 2048);
                b2f[ei] = *(const f16x8*)(buf + baseB2 + ei * 2048);
            }
            __builtin_amdgcn_s_setprio(1);
            #pragma unroll
            for (int mi = 0; mi < 4; mi++)
                #pragma unroll
                for (int ei = 0; ei < 4; ei++) {
                    hi[mi][ei] = __builtin_amdgcn_mfma_f32_16x16x32_f16(a1[mi], b1f[ei], hi[mi][ei], 0, 0, 0);
                    lo[mi][ei] = __builtin_amdgcn_mfma_f32_16x16x32_f16(a1[mi], b2f[ei], lo[mi][ei], 0, 0, 0);
                    lo[mi][ei] = __builtin_amdgcn_mfma_f32_16x16x32_f16(a2[mi], b1f[ei], lo[mi][ei], 0, 0, 0);
                }
            __builtin_amdgcn_s_setprio(0);
        }

        // epilogue: running argmin (ascending e, strict <); e2 from LDS
        #pragma unroll
        for (int ei = 0; ei < 4; ei++) {
            const int eloc = et * 128 + we * 64 + ei * 16 + l15;
            const float ev = lds_e2[eloc];
            const int eix = eh * 512 + eloc;
            #pragma unroll
            for (int mi = 0; mi < 4; mi++) {
                f32x4 dot4 = hi[mi][ei] + lo[mi][ei] * (1.0f / 4096.0f);
                #pragma unroll
                for (int rr = 0; rr < 4; rr++) {
                    float d = ev - 2.0f * dot4[rr];
                    int s = mi * 4 + rr;
                    if (d < rm[s]) { rm[s] = d; ri[s] = eix; }
                }
                hi[mi][ei] = (f32x4){0.f, 0.f, 0.f, 0.f};
                lo[mi][ei] = (f32x4){0.f, 0.f, 0.f, 0.f};
            }
        }
    }

    // cross-lane reduce over the 16 lanes sharing the same rows
    #pragma unroll
    for (int m = 1; m < 16; m <<= 1) {
        #pragma unroll
        for (int s = 0; s < 16; s++) {
            float ov = __shfl_xor(rm[s], m);
            int oi = __shfl_xor(ri[s], m);
            if (ov < rm[s] || (ov == rm[s] && oi < ri[s])) { rm[s] = ov; ri[s] = oi; }
        }
    }

    // merge the 2 waves sharing each row range (mv/miv reuse buf0; all
    // k-loop reads done before the final __syncthreads below)
    float* mv = (float*)smem;           // [128][2]
    int* miv = (int*)(smem + 1024);     // [128][2]
    __syncthreads();
    if (l15 == 0) {
        #pragma unroll
        for (int s = 0; s < 16; s++) {
            int mi = s >> 2, rr = s & 3;
            int rloc = wm * 64 + mi * 16 + (lane >> 4) * 4 + rr;
            mv[rloc * 2 + we] = rm[s];
            miv[rloc * 2 + we] = ri[s];
        }
    }
    __syncthreads();
    if (t < 128) {
        float v0 = mv[t * 2], v1 = mv[t * 2 + 1];
        int i0 = miv[t * 2], i1 = miv[t * 2 + 1];
        bool take1 = (v1 < v0) || (v1 == v0 && i1 < i0);
        float bv = take1 ? v1 : v0;
        int bi = take1 ? i1 : i0;
        // packed deterministic cross-block min-merge: sortable f32 | idx
        unsigned int u = __float_as_uint(bv);
        unsigned int su = (u & 0x80000000u) ? ~u : (u ^ 0x80000000u);
        unsigned long long packed = ((unsigned long long)su << 32) | (unsigned int)bi;
        atomicMin(&pk[ch * kN + n0 + t], packed);
    }
}

// ================= gather (cp-XCD affine) + fused loss =====================
__global__ __launch_bounds__(256) void gather_pk(
    const float* __restrict__ cb, const unsigned long long* __restrict__ pk,
    const float* __restrict__ partials, float* __restrict__ out,
    float* __restrict__ loss)
{
    const int t = threadIdx.x;
    const int lane = t & 63, q = t >> 6;
    const int b = blockIdx.x;
    const int cp = b & 7;            // channel -> XCD affinity (cb panel L2-fits)
    const int bt = (b >> 3) & 63;    // 64 bin-tiles of 16
    const int ftile = (b >> 9) & 7;  // 8 frame tiles of 64
    const int bb = b >> 12;          // batch
    const int co = (kC - 1) - cp;
    const int f = ftile * 64 + lane;
    const int n = bb * kFrames + f;
    const int e = (int)(unsigned int)(pk[cp * kN + n] & 0xFFFFFFFFull);
    const int bin0 = bt * 16 + q * 4;
    const float4 v4 = *(const float4*)&cb[((size_t)cp * kE + e) * kBins + bin0];
    const size_t base = ((size_t)(bb * kC + co) * kBins + bin0) * kFrames + f;
    out[base] = v4.x;
    out[base + kFrames] = v4.y;
    out[base + 2 * (size_t)kFrames] = v4.z;
    out[base + 3 * (size_t)kFrames] = v4.w;

    // one designated block also computes the loss (pk/partials are complete
    // before this kernel launches; runs concurrently with other blocks)
    if (b == 32767) {
        __shared__ float reds[256];
        float s = 0.f;
        for (int i = t; i < kC * kN; i += 256) {
            unsigned int su = (unsigned int)(pk[i] >> 32);
            unsigned int u = (su & 0x80000000u) ? (su ^ 0x80000000u) : ~su;
            s += __uint_as_float(u);
        }
        for (int i = t; i < 4096; i += 256) s += partials[i];
        reds[t] = s;
        __syncthreads();
        for (int off = 128; off > 0; off >>= 1) {
            if (t < off) reds[t] += reds[t + off];
            __syncthreads();
        }
        if (t == 0) loss[0] = 1.25f * reds[0] / (float)(kN * kBins);
    }
}

} // namespace

extern "C" void kernel_launch(void* const* d_in, const int* in_sizes, int n_in,
                              void* d_out, int out_size, void* d_ws, size_t ws_size,
                              hipStream_t stream)
{
    const float* x   = (const float*)d_in[0];
    const float* w1  = (const float*)d_in[1];
    const float* b1  = (const float*)d_in[2];
    const float* w2  = (const float*)d_in[3];
    const float* b2  = (const float*)d_in[4];
    const float* wsk = (const float*)d_in[5];
    const float* bsk = (const float*)d_in[6];
    const float* cb  = (const float*)d_in[7];
    float* out = (float*)d_out;
    char* ws = (char*)d_ws;

    // ws layout: B1|B2 32M | e2 32K | pk 256K | partials 16K
    _Float16* B1 = (_Float16*)ws;
    float* e2                  = (float*)(ws + 33554432);
    unsigned long long* pk     = (unsigned long long*)(ws + 33554432 + 32768);
    float* partials            = (float*)(ws + 33554432 + 32768 + 262144);
    _Float16* V1 = (_Float16*)d_out; // V1 67MB | V2 67MB, overwritten by gather

    conv_fused_v2<<<dim3(kBins / BT, kFrames / FT, kB), 256, 0, stream>>>(
        x, w1, b1, w2, b2, wsk, bsk, V1, partials);
    cbsplit_e2<<<(kC * kE) / 4, 256, 0, stream>>>(cb, B1, e2, pk);
    dist_mfma<<<dim3(512), 256, 0, stream>>>(V1, B1, e2, pk);
    gather_pk<<<dim3(32768), 256, 0, stream>>>(cb, pk, partials, out,
                                               out + (size_t)kC * kBins * kN);
}